// Round 4
// baseline (346.980 us; speedup 1.0000x reference)
//
#include <hip/hip_runtime.h>
#include <stdint.h>
#include <math.h>

#define NALPH 128
#define NEMB  128
#define NST   512
#define BATCH 256
#define TLEN  256
#define FANIN 640   // NEMB + NST

// NOTE: no __has_builtin guards anywhere that affect control flow — host and
// device preprocessor passes MUST agree (R11 failed because they didn't:
// host launched the WqT variant into the device's WsF-expecting kernel).
// Target is gfx950: sdot4 and i8-MFMA builtins exist.
#define SDOT4(a, b, c) __builtin_amdgcn_sdot4((a), (b), (c), false)
typedef __attribute__((ext_vector_type(4))) int i32x4;

// ---------------------------------------------------------------------------
// k_prep (896 blocks x 256 thr):
//  [0,256)    G[tok*512+n] = b_in[n] + sum_e emb[tok,e]*W_in[n,e]  (fp32 exact)
//  [256,768)  W_s row-quant: WqT[kg*512+n] (sdot layout, kept for fallback use)
//             AND MFMA B-frag order WsF[((nt*8+c)*64+lane)*4+d]; Sd[n]=mx/16129
//  [768,896)  W_out row-quant: WoQ[j*128+a] (k_out_i8 layout); So[a]=mx/16129
// Frag mapping (dword kd of a 512B row r): c=kd>>4, hi=(kd>>2)&3, d=kd&3,
// lane=hi*16+(r&15), tile=r>>4 — standard B[k][n]: lane holds col n=lane&15,
// k-bytes (lane>>4)*16 + 4d+b of each 64B chunk c.
// ---------------------------------------------------------------------------
__global__ __launch_bounds__(256) void k_prep(
    const float* __restrict__ emb, const float* __restrict__ W_in,
    const float* __restrict__ b_in, const float* __restrict__ W_out,
    float* __restrict__ G, int* __restrict__ WqT, float* __restrict__ Sd,
    int* __restrict__ WoQ, float* __restrict__ So, int* __restrict__ WsF)
{
  int bid = blockIdx.x, tid = threadIdx.x;
  if (bid < 256) {
    int idx = bid * 256 + tid;           // tok*512 + n
    int tok = idx >> 9, n = idx & 511;
    const float* er = emb + tok * NEMB;
    const float* wr = W_in + (size_t)n * FANIN;
    float acc = b_in[n];
#pragma unroll 8
    for (int e = 0; e < NEMB; ++e) acc += er[e] * wr[e];
    G[idx] = acc;
  } else if (bid < 768) {
    int n = bid - 256;                   // W_s row
    __shared__ float smax[128];
    float lw[4]; float m = 0.f;
    if (tid < 128) {
      const float* wr = W_in + (size_t)n * FANIN + NEMB + tid * 4;
#pragma unroll
      for (int i = 0; i < 4; ++i) { lw[i] = wr[i]; m = fmaxf(m, fabsf(lw[i])); }
      smax[tid] = m;
    }
    __syncthreads();
    for (int s2 = 64; s2 > 0; s2 >>= 1) {
      if (tid < s2) smax[tid] = fmaxf(smax[tid], smax[tid + s2]);
      __syncthreads();
    }
    float mx = smax[0];
    if (tid < 128) {
      float r = 127.f / mx;
      uint32_t pk = 0;
#pragma unroll
      for (int i = 0; i < 4; ++i) {
        int qv = (int)rintf(lw[i] * r);
        qv = qv < -127 ? -127 : (qv > 127 ? 127 : qv);
        pk |= (uint32_t)(qv & 0xff) << (8 * i);
      }
      WqT[tid * NST + n] = (int)pk;      // sdot layout (kept)
      int kd = tid;
      int c = kd >> 4, hi = (kd >> 2) & 3, d = kd & 3;
      int lane = hi * 16 + (n & 15), nt = n >> 4;
      WsF[(((nt * 8 + c) * 64) + lane) * 4 + d] = (int)pk;  // MFMA B-frag
    }
    if (tid == 0) Sd[n] = mx / 16129.0f;
  } else {
    int a = bid - 768;                   // W_out row
    __shared__ float smax[128];
    float lw[4]; float m = 0.f;
    if (tid < 128) {
      const float* wr = W_out + (size_t)a * NST + tid * 4;
#pragma unroll
      for (int i = 0; i < 4; ++i) { lw[i] = wr[i]; m = fmaxf(m, fabsf(lw[i])); }
      smax[tid] = m;
    }
    __syncthreads();
    for (int s2 = 64; s2 > 0; s2 >>= 1) {
      if (tid < s2) smax[tid] = fmaxf(smax[tid], smax[tid + s2]);
      __syncthreads();
    }
    float mx = smax[0];
    if (tid < 128) {
      float r = 127.f / mx;
      uint32_t pk = 0;
#pragma unroll
      for (int i = 0; i < 4; ++i) {
        int qv = (int)rintf(lw[i] * r);
        qv = qv < -127 ? -127 : (qv > 127 ? 127 : qv);
        pk |= (uint32_t)(qv & 0xff) << (8 * i);
      }
      WoQ[tid * 128 + a] = (int)pk;      // k_out_i8 layout
    }
    if (tid == 0) So[a] = mx / 16129.0f;
  }
}

// ---------------------------------------------------------------------------
// k_rec R12 — MFMA recurrence (R11 math, now actually fed WsF).
// 256 blocks x 512 thr (8 waves, 2/SIMD). Wave wv owns n-tiles [wv*4,wv*4+4):
// B-frags Bf[4][8] = 128 dwords, loop-invariant, AGPR-residency is FREE for
// MFMA operands (v_dot4 could not read AGPRs — that was the R8-R10 copy tax).
// A = state broadcast from LDS (same-address per hi-group = conflict-free);
// all 16 A-rows replicated, so D[m][n] is m-independent; lanes hi==0 take
// reg0 (D row 0). col = lane&15 (m89-verified C/D mapping). Integer dots are
// bit-identical to the sdot path -> absmax must stay 0.009765625.
// ---------------------------------------------------------------------------
__global__ __launch_bounds__(512, 2) void k_rec(
    const int* __restrict__ w, const float* __restrict__ G,
    const int* __restrict__ WsF, const float* __restrict__ Sd,
    signed char* __restrict__ qstates)
{
  __shared__ __align__(16) signed char qs[2][NST];
  int tid  = threadIdx.x;
  int lane = tid & 63, wv = tid >> 6;
  int l15  = lane & 15, hi = lane >> 4;
  int row  = blockIdx.x;

  // B-fragments: 4 n-tiles x 8 k-chunks, 16B/lane, coalesced.
  const i32x4* wsf = (const i32x4*)WsF;
  i32x4 Bf[4][8];
#pragma unroll
  for (int q = 0; q < 4; ++q)
#pragma unroll
    for (int c = 0; c < 8; ++c)
      Bf[q][c] = wsf[((size_t)((wv * 4 + q) * 8 + c)) * 64 + lane];

  // Epilogue constants for active lanes (hi==0): n = wv*64 + q*16 + l15
  int n0 = wv * 64 + l15;
  float dn[4], g[4];
  const int* wr = w + row * TLEN;
  if (hi == 0) {
#pragma unroll
    for (int q = 0; q < 4; ++q) dn[q] = Sd[n0 + q * 16];
    int tok0 = wr[0];
#pragma unroll
    for (int q = 0; q < 4; ++q) g[q] = G[tok0 * NST + n0 + q * 16];
  }

  qs[0][tid] = 0;
  __syncthreads();

  signed char* qrow = qstates + (size_t)row * TLEN * NST + n0;

  int p = 0;
  for (int t = 0; t < TLEN; ++t) {
    int tok_n = (t < TLEN - 1) ? wr[t + 1] : 0;
    float g_n[4];
    if (hi == 0) {
#pragma unroll
      for (int q = 0; q < 4; ++q) g_n[q] = G[tok_n * NST + n0 + q * 16];
    }

    // A-fragments: chunk c -> state bytes [c*64 + hi*16, +16)
    i32x4 A[8];
#pragma unroll
    for (int c = 0; c < 8; ++c)
      A[c] = *(const i32x4*)(qs[p] + c * 64 + hi * 16);

    i32x4 acc0 = {0,0,0,0}, acc1 = {0,0,0,0}, acc2 = {0,0,0,0}, acc3 = {0,0,0,0};
#pragma unroll
    for (int c = 0; c < 8; ++c) {
      acc0 = __builtin_amdgcn_mfma_i32_16x16x64_i8(A[c], Bf[0][c], acc0, 0, 0, 0);
      acc1 = __builtin_amdgcn_mfma_i32_16x16x64_i8(A[c], Bf[1][c], acc1, 0, 0, 0);
      acc2 = __builtin_amdgcn_mfma_i32_16x16x64_i8(A[c], Bf[2][c], acc2, 0, 0, 0);
      acc3 = __builtin_amdgcn_mfma_i32_16x16x64_i8(A[c], Bf[3][c], acc3, 0, 0, 0);
    }

    if (hi == 0) {
      int v[4] = { acc0[0], acc1[0], acc2[0], acc3[0] };  // D row 0
#pragma unroll
      for (int q = 0; q < 4; ++q) {
        float a = g[q] + (float)v[q] * dn[q];
        a = fminf(fmaxf(a, -15.f), 15.f);
        float e = __expf(2.f * a);         // tanh = 1 - 2/(e^(2a)+1)
        float s = fmaf(-2.f, __builtin_amdgcn_rcpf(e + 1.f), 1.f);
        signed char q8 = (signed char)(int)rintf(s * 127.f);
        qs[p ^ 1][n0 + q * 16] = q8;
        qrow[(size_t)t * NST + q * 16] = q8;
        g[q] = g_n[q];
      }
    }
    __syncthreads();
    p ^= 1;
  }
}

// ---------------------------------------------------------------------------
// k_out_i8 — THE proven epilogue (this is what actually ran in every passing
// round; the old k_out_mfma never launched due to the host/device #if split).
// ---------------------------------------------------------------------------
__global__ __launch_bounds__(256) void k_out_i8(
    const signed char* __restrict__ qstates, const int* __restrict__ WoQ,
    const float* __restrict__ So, const float* __restrict__ b_out,
    float* __restrict__ y)
{
  __shared__ __align__(16) int sl[32 * 128];   // 16 KB
  int tid = threadIdx.x;
  size_t bt0 = (size_t)blockIdx.x * 32;
  const int4* gp = (const int4*)(qstates + bt0 * NST);
  int4* slp = (int4*)sl;
#pragma unroll
  for (int i = 0; i < 4; ++i) slp[tid + 256 * i] = gp[tid + 256 * i];
  __syncthreads();

  int a0 = tid & 63, gidx = tid >> 6;
  const int* slg = sl + gidx * 8 * 128;
  int acc0[8], acc1[8];
#pragma unroll
  for (int r = 0; r < 8; ++r) { acc0[r] = 0; acc1[r] = 0; }

  for (int j4 = 0; j4 < 32; ++j4) {
    int w00 = WoQ[(4 * j4 + 0) * 128 + a0];
    int w01 = WoQ[(4 * j4 + 0) * 128 + a0 + 64];
    int w10 = WoQ[(4 * j4 + 1) * 128 + a0];
    int w11 = WoQ[(4 * j4 + 1) * 128 + a0 + 64];
    int w20 = WoQ[(4 * j4 + 2) * 128 + a0];
    int w21 = WoQ[(4 * j4 + 2) * 128 + a0 + 64];
    int w30 = WoQ[(4 * j4 + 3) * 128 + a0];
    int w31 = WoQ[(4 * j4 + 3) * 128 + a0 + 64];
#pragma unroll
    for (int r = 0; r < 8; ++r) {
      int4 s = *(const int4*)&slg[r * 128 + 4 * j4];
      acc0[r] = SDOT4(w00, s.x, acc0[r]);
      acc1[r] = SDOT4(w01, s.x, acc1[r]);
      acc0[r] = SDOT4(w10, s.y, acc0[r]);
      acc1[r] = SDOT4(w11, s.y, acc1[r]);
      acc0[r] = SDOT4(w20, s.z, acc0[r]);
      acc1[r] = SDOT4(w21, s.z, acc1[r]);
      acc0[r] = SDOT4(w30, s.w, acc0[r]);
      acc1[r] = SDOT4(w31, s.w, acc1[r]);
    }
  }

  float s0 = So[a0], s1 = So[a0 + 64];
  float b0 = b_out[a0], b1 = b_out[a0 + 64];
#pragma unroll
  for (int r = 0; r < 8; ++r) {
    size_t rowb = (bt0 + gidx * 8 + r) * 128;
    y[rowb + a0]      = (float)acc0[r] * s0 + b0;
    y[rowb + a0 + 64] = (float)acc1[r] * s1 + b1;
  }
}

// ---------------------------------------------------------------------------
extern "C" void kernel_launch(void* const* d_in, const int* in_sizes, int n_in,
                              void* d_out, int out_size, void* d_ws, size_t ws_size,
                              hipStream_t stream) {
  const int*   w     = (const int*)d_in[0];
  const float* emb   = (const float*)d_in[1];
  const float* W_in  = (const float*)d_in[2];
  const float* b_in  = (const float*)d_in[3];
  const float* W_out = (const float*)d_in[4];
  const float* b_out = (const float*)d_in[5];
  float* y = (float*)d_out;

  char* ws = (char*)d_ws;
  float*       G       = (float*)ws;                        // 256 KB
  int*         WqT     = (int*)(ws + (256 << 10));          // 256 KB
  float*       Sd      = (float*)(ws + (512 << 10));        // 2 KB
  int*         WoQ     = (int*)(ws + (576 << 10));          // 64 KB
  float*       So      = (float*)(ws + (640 << 10));        // 0.5 KB
  int*         WsF     = (int*)(ws + (704 << 10));          // 256 KB frag-order
  signed char* qstates = (signed char*)(ws + (1024 << 10)); // 32 MB i8

  k_prep<<<896, 256, 0, stream>>>(emb, W_in, b_in, W_out, G, WqT, Sd, WoQ, So, WsF);
  k_rec <<<BATCH, 512, 0, stream>>>(w, G, WsF, Sd, qstates);
  k_out_i8<<<BATCH * TLEN / 32, 256, 0, stream>>>(qstates, WoQ, So, b_out, y);
}